// Round 7
// baseline (426.311 us; speedup 1.0000x reference)
//
#include <hip/hip_runtime.h>
#include <hip/hip_fp16.h>
#include <stdint.h>

#define IN    4096
#define OUT   4096
#define BATCH 8192
#define TK    64
#define BT    8     // batch rows per block in the spmm kernel

// ---------------------------------------------------------------------------
// Kernel 1: ONE WAVE PER ROW top-K.
//  - 16-round MSB-greedy threshold search on the TOP 16 BITS of the
//    order-preserving key transform; exact tie resolution in the boundary
//    bucket via 28-round ballot search over (low16<<12)|(4095-idx)
//    (inverted idx matches jax.lax.top_k smaller-index tie preference).
//  - TWO-CHOICE bank-quad assignment: spmm stages x twice in LDS,
//    copy0: row i quad i&7;  copy1: row slot 4096+(i^((i>>3)&7)), quad
//    (i^(i>>3))&7. Each selected item can serve a position-class via q0 or
//    q1; 3-tier matching (native q0 / overflow->q1 / fallback) cuts the
//    defect rate ~13% -> ~3%, so spmm's step-k gather is near-uniform over
//    the 8 LDS bank quads. Any assignment is CORRECT (bijective positions +
//    valid lrow); tiers only affect speed.
//  - wt payload: {lrow, fp16(val) duplicated} feeding v_pk_fma_f16.
// ---------------------------------------------------------------------------
__global__ __launch_bounds__(256)
void topk_build_kernel(const float* __restrict__ pre_w,
                       const float* __restrict__ sign_m,
                       int2* __restrict__ wt) {
  __shared__ int selbuf[4][TK];
  __shared__ uint32_t bucket[4][128];

  const int wid  = threadIdx.x >> 6;
  const int lane = threadIdx.x & 63;
  const int row  = blockIdx.x * 4 + wid;
  const float* pw = pre_w + (size_t)row * IN;
  const uint64_t lt = (1ull << lane) - 1ull;

  // load 64 keys per lane; keys[j*4+c] <-> global index j*256 + lane*4 + c
  uint32_t keys[64];
  #pragma unroll
  for (int j = 0; j < 16; ++j) {
    const float4 v = *(const float4*)(pw + j * 256 + lane * 4);
    const uint32_t u0 = __float_as_uint(v.x);
    const uint32_t u1 = __float_as_uint(v.y);
    const uint32_t u2 = __float_as_uint(v.z);
    const uint32_t u3 = __float_as_uint(v.w);
    keys[j * 4 + 0] = (u0 & 0x80000000u) ? ~u0 : (u0 | 0x80000000u);
    keys[j * 4 + 1] = (u1 & 0x80000000u) ? ~u1 : (u1 | 0x80000000u);
    keys[j * 4 + 2] = (u2 & 0x80000000u) ? ~u2 : (u2 | 0x80000000u);
    keys[j * 4 + 3] = (u3 & 0x80000000u) ? ~u3 : (u3 | 0x80000000u);
  }

  // ---- phase A: largest 16-bit prefix P with count(key>>16 >= P) >= TK ----
  uint32_t curH = 0u;
  for (int b = 15; b >= 0; --b) {
    const uint32_t candF = (curH | (1u << b)) << 16;
    int c = 0;
    #pragma unroll
    for (int i = 0; i < 64; ++i) c += (keys[i] >= candF) ? 1 : 0;
    #pragma unroll
    for (int off = 32; off > 0; off >>= 1) c += __shfl_xor(c, off, 64);
    if (c >= TK) curH |= (1u << b);
  }

  // strict-above count ng and bucket count nb (packed 16|16 single reduce)
  int pk = 0;
  #pragma unroll
  for (int i = 0; i < 64; ++i) {
    const uint32_t kh = keys[i] >> 16;
    pk += (kh > curH) ? 1 : 0;
    pk += (kh == curH) ? (1 << 16) : 0;
  }
  #pragma unroll
  for (int off = 32; off > 0; off >>= 1) pk += __shfl_xor(pk, off, 64);
  const int ng = pk & 0xFFFF;
  const int nb = pk >> 16;
  const int m  = TK - ng;            // 1..TK entries to take from the bucket

  // ---- phase B: collect bucket, find m-th largest packed value ----
  {
    int base = 0;
    #pragma unroll
    for (int i = 0; i < 64; ++i) {
      const bool hit = (keys[i] >> 16) == curH;
      const uint64_t msk = __ballot(hit);
      if (hit) {
        const int p = base + (int)__popcll(msk & lt);
        const int idx = (i >> 2) * 256 + lane * 4 + (i & 3);
        if (p < 128) bucket[wid][p] = ((keys[i] & 0xFFFFu) << 12) | (uint32_t)(4095 - idx);
      }
      base += (int)__popcll(msk);
    }
  }
  __syncthreads();

  uint32_t curB = 0u;
  if (nb != m) {                      // nb==m -> take the whole bucket, skip search
    const uint32_t v0 = (lane      < nb) ? bucket[wid][lane]      : 0u;
    const uint32_t v1 = (lane + 64 < nb) ? bucket[wid][lane + 64] : 0u;
    for (int b = 27; b >= 0; --b) {
      const uint32_t cand = curB | (1u << b);
      const int c = (int)__popcll(__ballot(v0 >= cand)) + (int)__popcll(__ballot(v1 >= cand));
      if (c >= m) curB = cand;
    }
  }

  // ---- emission: compact the exact selection set into selbuf ----
  {
    int base = 0;
    #pragma unroll
    for (int i = 0; i < 64; ++i) {
      const uint32_t kh = keys[i] >> 16;
      const int idx = (i >> 2) * 256 + lane * 4 + (i & 3);
      const uint32_t packed = ((keys[i] & 0xFFFFu) << 12) | (uint32_t)(4095 - idx);
      const bool sel = (kh > curH) || ((kh == curH) && (packed >= curB));
      const uint64_t msk = __ballot(sel);
      if (sel) selbuf[wid][base + (int)__popcll(msk & lt)] = idx;
      base += (int)__popcll(msk);
    }
  }
  __syncthreads();

  // ---- two-choice bank-quad position assignment (all ballots convergent) ----
  const int myidx = selbuf[wid][lane];   // exactly TK=64 entries = 64 lanes
  const int q0 = myidx & 7;
  const int q1 = (myidx ^ (myidx >> 3)) & 7;

  // tier 1: natives by q0 (rank < 8 guaranteed a slot in q0's class)
  uint64_t m0 = 0ull;
  int cnt0[8];
  #pragma unroll
  for (int j = 0; j < 8; ++j) {
    const uint64_t mm = __ballot(q0 == j);
    cnt0[j] = (int)__popcll(mm);
    if (q0 == j) m0 = mm;
  }
  const int r0 = (int)__popcll(m0 & lt);
  const bool t1 = (r0 < 8);

  int g[8];                                  // tier-1 fill per quad
  #pragma unroll
  for (int j = 0; j < 8; ++j) g[j] = (cnt0[j] < 8) ? cnt0[j] : 8;

  // tier 2: q0-overflow items try q1 (second hash choice)
  uint64_t m1 = 0ull;
  int cnt2[8];
  #pragma unroll
  for (int j = 0; j < 8; ++j) {
    const uint64_t mm = __ballot(!t1 && (q1 == j));
    cnt2[j] = (int)__popcll(mm);
    if (!t1 && (q1 == j)) m1 = mm;
  }
  const int r1 = (int)__popcll(m1 & lt);
  int gq1 = 0, fq1 = 0;
  #pragma unroll
  for (int j = 0; j < 8; ++j) if (q1 == j) { gq1 = g[j]; fq1 = 8 - g[j]; }
  const bool t2 = (!t1) && (r1 < fq1);

  // capacity used per quad after tiers 1+2
  int u[8];
  #pragma unroll
  for (int j = 0; j < 8; ++j) {
    const int fr = 8 - g[j];
    const int a2 = (cnt2[j] < fr) ? cnt2[j] : fr;
    u[j] = g[j] + a2;
  }

  // tier 3 rank (ballot in straight-line code)
  const bool t3 = (!t1) && (!t2);
  const int R = (int)__popcll(__ballot(t3) & lt);

  int pos, lrow;
  if (t1) {
    pos  = ((q0 - row) & 7) + 8 * r0;
    lrow = myidx;                                        // copy 0
  } else if (t2) {
    pos  = ((q1 - row) & 7) + 8 * (gq1 + r1);
    lrow = 4096 + (myidx ^ ((myidx >> 3) & 7));          // copy 1
  } else {
    int posf = -1, acc = 0;
    #pragma unroll
    for (int cc = 0; cc < 8; ++cc) {                     // classes in order
      int uu = 0;
      #pragma unroll
      for (int j = 0; j < 8; ++j)
        if (((row + cc) & 7) == j) uu = u[j];
      const int f2 = 8 - uu;
      if (posf < 0 && R < acc + f2) posf = cc + 8 * (uu + (R - acc));
      acc += f2;
    }
    pos  = posf;
    lrow = myidx;                                        // copy 0 (off-quad, rare)
  }

  const float v = expf(pw[myidx]) * sign_m[(size_t)row * IN + myidx];
  const uint32_t hb = (uint32_t)__half_as_ushort(__float2half_rn(v));
  int2* dst = wt + (((size_t)(pos >> 1) * OUT + row) * 2 + (pos & 1));
  *dst = make_int2(lrow, (int)(hb | (hb << 16)));
}

// ---------------------------------------------------------------------------
// Kernel 2: sparse matmul. Block = BT batch rows x all OUT outputs.
// x staged TWICE in LDS fp16 transposed (128 KB): copy0 row i at slot i,
// copy1 at slot 4096+(i^((i>>3)&7)) (rotated quad). wt's lrow picks the copy.
// Stage ownership is stride-1024 (thread t owns features t,t+1024,...) so
// both copies' ds_write_b128 are quad-uniform (conflict-free).
// Per (o,k): 1x ds_read_b128 gather + 4x v_pk_fma_f16; fully-unrolled k-loop
// with 2x int4 register prefetch; fp16 accumulation in 4 static chains,
// fp32 combine.
// ---------------------------------------------------------------------------
__device__ __forceinline__ uint32_t pack_f16x2(float a, float b) {
  const uint32_t lo = __half_as_ushort(__float2half(a));
  const uint32_t hi = __half_as_ushort(__float2half(b));
  return lo | (hi << 16);
}

__global__ __launch_bounds__(1024, 4)   // 128 KB LDS -> 1 block/CU (16 waves)
void spmm_topk_kernel(const float* __restrict__ x,
                      const int4* __restrict__ wt4,
                      float* __restrict__ out) {
  __shared__ uint16_t ldsx[2 * IN * BT];   // 128 KB: two quad-mapped copies

  const int tid = threadIdx.x;
  const int b0 = blockIdx.x * BT;

  // ---- stage: 8 rows of x -> LDS fp16 transposed, two copies ----
  {
    #pragma unroll
    for (int rr = 0; rr < 4; ++rr) {
      const int f = tid + rr * 1024;       // stride-1024 feature ownership
      float a[BT];
      #pragma unroll
      for (int j = 0; j < BT; ++j)
        a[j] = __builtin_nontemporal_load(x + (size_t)(b0 + j) * IN + f);
      uint4 pkv;
      pkv.x = pack_f16x2(a[0], a[1]);
      pkv.y = pack_f16x2(a[2], a[3]);
      pkv.z = pack_f16x2(a[4], a[5]);
      pkv.w = pack_f16x2(a[6], a[7]);
      *(uint4*)(&ldsx[f * BT]) = pkv;                              // copy 0
      const int f1 = 4096 + (f ^ ((f >> 3) & 7));
      *(uint4*)(&ldsx[f1 * BT]) = pkv;                             // copy 1
    }
  }
  __syncthreads();

  const int wave = tid >> 6;
  const int lane = tid & 63;

  for (int g = wave; g < (OUT / 64); g += 16) {   // 4 groups per wave
    const int o = g * 64 + lane;
    const int4* wq = wt4 + o;                     // element k2 at wq[k2*OUT]

    __half2 acc0[4], acc1[4], acc2[4], acc3[4];   // 4 chains x 4 batch-pairs
    #pragma unroll
    for (int j = 0; j < 4; ++j) {
      acc0[j] = __float2half2_rn(0.f);
      acc1[j] = __float2half2_rn(0.f);
      acc2[j] = __float2half2_rn(0.f);
      acc3[j] = __float2half2_rn(0.f);
    }

    int4 p0 = wq[0];
    int4 p1 = wq[OUT];

    #pragma unroll
    for (int k2 = 0; k2 < (TK / 2); k2 += 2) {    // 4 k-entries per iter
      int4 n0, n1;
      if (k2 + 2 < (TK / 2)) {                    // prefetch next group (static)
        n0 = wq[(size_t)(k2 + 2) * OUT];
        n1 = wq[(size_t)(k2 + 3) * OUT];
      }
      const uint4 xa = *(const uint4*)(&ldsx[p0.x * BT]);   // quad-matched gathers
      const uint4 xb = *(const uint4*)(&ldsx[p0.z * BT]);
      const uint4 xc = *(const uint4*)(&ldsx[p1.x * BT]);
      const uint4 xd = *(const uint4*)(&ldsx[p1.z * BT]);
      const __half2 va = *(const __half2*)&p0.y;
      const __half2 vb = *(const __half2*)&p0.w;
      const __half2 vc = *(const __half2*)&p1.y;
      const __half2 vd = *(const __half2*)&p1.w;
      const __half2* ha = (const __half2*)&xa;
      const __half2* hb = (const __half2*)&xb;
      const __half2* hc = (const __half2*)&xc;
      const __half2* hd = (const __half2*)&xd;
      #pragma unroll
      for (int j = 0; j < 4; ++j) {
        acc0[j] = __hfma2(ha[j], va, acc0[j]);
        acc1[j] = __hfma2(hb[j], vb, acc1[j]);
        acc2[j] = __hfma2(hc[j], vc, acc2[j]);
        acc3[j] = __hfma2(hd[j], vd, acc3[j]);
      }
      if (k2 + 2 < (TK / 2)) { p0 = n0; p1 = n1; }
    }

    // epilogue: combine 4 fp16 chains in fp32, plain stores
    float* op = out + (size_t)b0 * OUT + o;
    #pragma unroll
    for (int j = 0; j < 4; ++j) {
      const float lo = (__low2float(acc0[j])  + __low2float(acc1[j])) +
                       (__low2float(acc2[j])  + __low2float(acc3[j]));
      const float hi = (__high2float(acc0[j]) + __high2float(acc1[j])) +
                       (__high2float(acc2[j]) + __high2float(acc3[j]));
      op[(size_t)(2 * j) * OUT]     = lo;
      op[(size_t)(2 * j + 1) * OUT] = hi;
    }
  }
}

// ---------------------------------------------------------------------------
extern "C" void kernel_launch(void* const* d_in, const int* in_sizes, int n_in,
                              void* d_out, int out_size, void* d_ws, size_t ws_size,
                              hipStream_t stream) {
  const float* x      = (const float*)d_in[0];
  const float* pre_w  = (const float*)d_in[1];
  const float* sign_m = (const float*)d_in[2];
  float* out = (float*)d_out;

  topk_build_kernel<<<OUT / 4, 256, 0, stream>>>(pre_w, sign_m, (int2*)d_ws);
  spmm_topk_kernel<<<BATCH / BT, 1024, 0, stream>>>(x, (const int4*)d_ws, out);
}

// Round 8
// 392.674 us; speedup vs baseline: 1.0857x; 1.0857x over previous
//
#include <hip/hip_runtime.h>
#include <hip/hip_fp16.h>
#include <stdint.h>

#define IN    4096
#define OUT   4096
#define BATCH 8192
#define TK    64
#define BT    8     // batch rows per block in the spmm kernel
#define ALT   1024  // features covered by the partial second (quad-rotated) copy

typedef float  fx4 __attribute__((ext_vector_type(4)));   // native vector for nt-load

// ---------------------------------------------------------------------------
// Kernel 1: ONE WAVE PER ROW top-K.
//  - 16-round MSB-greedy threshold search on the TOP 16 BITS of the
//    order-preserving key transform; exact tie resolution in the boundary
//    bucket via 28-round ballot search over (low16<<12)|(4095-idx)
//    (inverted idx matches jax.lax.top_k smaller-index tie preference).
//  - bank-quad position scheduling with PARTIAL two-choice: spmm stages a
//    full copy (rows 0..4095, quad i&7) plus a 16 KB rotated copy of rows
//    0..1023 at slot 4096+(i^((i>>3)&7)) (quad (i^(i>>3))&7). Tier-1 places
//    natives; tier-2 reroutes overflow items with idx<1024 through the
//    rotated copy; tier-3 fills remaining slots (fail-soft: any assignment
//    is correct, tiers only affect bank-conflict rate).
//  - wt payload: {lds_row, fp16(val) duplicated} feeding v_pk_fma_f16.
// ---------------------------------------------------------------------------
__global__ __launch_bounds__(256)
void topk_build_kernel(const float* __restrict__ pre_w,
                       const float* __restrict__ sign_m,
                       int2* __restrict__ wt) {
  __shared__ int selbuf[4][TK];
  __shared__ uint32_t bucket[4][128];

  const int wid  = threadIdx.x >> 6;
  const int lane = threadIdx.x & 63;
  const int row  = blockIdx.x * 4 + wid;
  const float* pw = pre_w + (size_t)row * IN;
  const uint64_t lt = (1ull << lane) - 1ull;

  // load 64 keys per lane; keys[j*4+c] <-> global index j*256 + lane*4 + c
  uint32_t keys[64];
  #pragma unroll
  for (int j = 0; j < 16; ++j) {
    const float4 v = *(const float4*)(pw + j * 256 + lane * 4);
    const uint32_t u0 = __float_as_uint(v.x);
    const uint32_t u1 = __float_as_uint(v.y);
    const uint32_t u2 = __float_as_uint(v.z);
    const uint32_t u3 = __float_as_uint(v.w);
    keys[j * 4 + 0] = (u0 & 0x80000000u) ? ~u0 : (u0 | 0x80000000u);
    keys[j * 4 + 1] = (u1 & 0x80000000u) ? ~u1 : (u1 | 0x80000000u);
    keys[j * 4 + 2] = (u2 & 0x80000000u) ? ~u2 : (u2 | 0x80000000u);
    keys[j * 4 + 3] = (u3 & 0x80000000u) ? ~u3 : (u3 | 0x80000000u);
  }

  // ---- phase A: largest 16-bit prefix P with count(key>>16 >= P) >= TK ----
  uint32_t curH = 0u;
  for (int b = 15; b >= 0; --b) {
    const uint32_t candF = (curH | (1u << b)) << 16;
    int c = 0;
    #pragma unroll
    for (int i = 0; i < 64; ++i) c += (keys[i] >= candF) ? 1 : 0;
    #pragma unroll
    for (int off = 32; off > 0; off >>= 1) c += __shfl_xor(c, off, 64);
    if (c >= TK) curH |= (1u << b);
  }

  // strict-above count ng and bucket count nb (packed 16|16 single reduce)
  int pk = 0;
  #pragma unroll
  for (int i = 0; i < 64; ++i) {
    const uint32_t kh = keys[i] >> 16;
    pk += (kh > curH) ? 1 : 0;
    pk += (kh == curH) ? (1 << 16) : 0;
  }
  #pragma unroll
  for (int off = 32; off > 0; off >>= 1) pk += __shfl_xor(pk, off, 64);
  const int ng = pk & 0xFFFF;
  const int nb = pk >> 16;
  const int m  = TK - ng;            // 1..TK entries to take from the bucket

  // ---- phase B: collect bucket, find m-th largest packed value ----
  {
    int base = 0;
    #pragma unroll
    for (int i = 0; i < 64; ++i) {
      const bool hit = (keys[i] >> 16) == curH;
      const uint64_t msk = __ballot(hit);
      if (hit) {
        const int p = base + (int)__popcll(msk & lt);
        const int idx = (i >> 2) * 256 + lane * 4 + (i & 3);
        if (p < 128) bucket[wid][p] = ((keys[i] & 0xFFFFu) << 12) | (uint32_t)(4095 - idx);
      }
      base += (int)__popcll(msk);
    }
  }
  __syncthreads();

  uint32_t curB = 0u;
  if (nb != m) {                      // nb==m -> take the whole bucket, skip search
    const uint32_t v0 = (lane      < nb) ? bucket[wid][lane]      : 0u;
    const uint32_t v1 = (lane + 64 < nb) ? bucket[wid][lane + 64] : 0u;
    for (int b = 27; b >= 0; --b) {
      const uint32_t cand = curB | (1u << b);
      const int c = (int)__popcll(__ballot(v0 >= cand)) + (int)__popcll(__ballot(v1 >= cand));
      if (c >= m) curB = cand;
    }
  }

  // ---- emission: compact the exact selection set into selbuf ----
  {
    int base = 0;
    #pragma unroll
    for (int i = 0; i < 64; ++i) {
      const uint32_t kh = keys[i] >> 16;
      const int idx = (i >> 2) * 256 + lane * 4 + (i & 3);
      const uint32_t packed = ((keys[i] & 0xFFFFu) << 12) | (uint32_t)(4095 - idx);
      const bool sel = (kh > curH) || ((kh == curH) && (packed >= curB));
      const uint64_t msk = __ballot(sel);
      if (sel) selbuf[wid][base + (int)__popcll(msk & lt)] = idx;
      base += (int)__popcll(msk);
    }
  }
  __syncthreads();

  // ---- partial two-choice bank-quad assignment (ballots convergent) ----
  const int myidx = selbuf[wid][lane];   // exactly TK=64 entries = 64 lanes
  const int q0 = myidx & 7;
  const int q1 = (myidx ^ (myidx >> 3)) & 7;
  const bool alt_ok = (myidx < ALT);     // rotated copy only covers rows 0..1023

  // tier 1: natives by q0 (rank < 8 guaranteed a slot in q0's class)
  uint64_t m0 = 0ull;
  int cnt0[8];
  #pragma unroll
  for (int j = 0; j < 8; ++j) {
    const uint64_t mm = __ballot(q0 == j);
    cnt0[j] = (int)__popcll(mm);
    if (q0 == j) m0 = mm;
  }
  const int r0 = (int)__popcll(m0 & lt);
  const bool t1 = (r0 < 8);

  int g[8];                                  // tier-1 fill per quad
  #pragma unroll
  for (int j = 0; j < 8; ++j) g[j] = (cnt0[j] < 8) ? cnt0[j] : 8;

  // tier 2: q0-overflow items with idx<ALT try q1 (rotated-copy choice)
  uint64_t m1 = 0ull;
  int cnt2[8];
  #pragma unroll
  for (int j = 0; j < 8; ++j) {
    const bool cand = (!t1) && alt_ok && (q1 == j);
    const uint64_t mm = __ballot(cand);
    cnt2[j] = (int)__popcll(mm);
    if (cand) m1 = mm;
  }
  const int r1 = (int)__popcll(m1 & lt);
  int gq1 = 0, fq1 = 0;
  #pragma unroll
  for (int j = 0; j < 8; ++j) if (q1 == j) { gq1 = g[j]; fq1 = 8 - g[j]; }
  const bool t2 = (!t1) && alt_ok && (r1 < fq1);

  // capacity used per quad after tiers 1+2
  int u[8];
  #pragma unroll
  for (int j = 0; j < 8; ++j) {
    const int fr = 8 - g[j];
    const int a2 = (cnt2[j] < fr) ? cnt2[j] : fr;
    u[j] = g[j] + a2;
  }

  // tier 3: remaining items -> remaining slots (rank via ballot)
  const bool t3 = (!t1) && (!t2);
  const int R = (int)__popcll(__ballot(t3) & lt);

  int pos, lrow;
  if (t1) {
    pos  = ((q0 - row) & 7) + 8 * r0;
    lrow = myidx;                                        // full copy
  } else if (t2) {
    pos  = ((q1 - row) & 7) + 8 * (gq1 + r1);
    lrow = 4096 + (myidx ^ ((myidx >> 3) & 7));          // rotated partial copy
  } else {
    int posf = -1, acc = 0;
    #pragma unroll
    for (int cc = 0; cc < 8; ++cc) {                     // classes in order
      int uu = 0;
      #pragma unroll
      for (int j = 0; j < 8; ++j)
        if (((row + cc) & 7) == j) uu = u[j];
      const int f2 = 8 - uu;
      if (posf < 0 && R < acc + f2) posf = cc + 8 * (uu + (R - acc));
      acc += f2;
    }
    pos  = posf;
    lrow = myidx;                                        // full copy (off-quad)
  }

  const float v = expf(pw[myidx]) * sign_m[(size_t)row * IN + myidx];
  const uint32_t hb = (uint32_t)__half_as_ushort(__float2half_rn(v));
  int2* dst = wt + (((size_t)(pos >> 1) * OUT + row) * 2 + (pos & 1));
  *dst = make_int2(lrow, (int)(hb | (hb << 16)));
}

// ---------------------------------------------------------------------------
// Kernel 2: sparse matmul (round-6 structure, +16 KB partial rotated copy).
// x staged in LDS fp16 transposed: full copy rows 0..4095 (row i at slot i)
// plus rotated copy of rows 0..1023 at slot 4096+(i^((i>>3)&7)). 80 KB total
// still fits 2 blocks/CU (160 KB LDS), so occupancy is unchanged vs 64 KB.
// Per (o,k): 1x ds_read_b128 gather + 4x v_pk_fma_f16; fully-unrolled k-loop
// with 2x int4 register prefetch; fp16 accumulation in 4 static chains,
// fp32 combine; plain out stores; nt x loads.
// ---------------------------------------------------------------------------
__device__ __forceinline__ uint32_t pack_f16x2(float a, float b) {
  const uint32_t lo = __half_as_ushort(__float2half(a));
  const uint32_t hi = __half_as_ushort(__float2half(b));
  return lo | (hi << 16);
}

__global__ __launch_bounds__(1024, 8)
void spmm_topk_kernel(const float* __restrict__ x,
                      const int4* __restrict__ wt4,
                      float* __restrict__ out) {
  __shared__ uint16_t ldsx[(IN + ALT) * BT];   // 80 KB

  const int tid = threadIdx.x;
  const int b0 = blockIdx.x * BT;

  // ---- stage: 8 rows of x -> LDS fp16 transposed (+ partial rotated copy) ----
  {
    const int i4 = tid * 4;            // this thread owns features i4..i4+3
    float c[4][BT];
    #pragma unroll
    for (int j = 0; j < BT; ++j) {
      const fx4* src = (const fx4*)(x + (size_t)(b0 + j) * IN + i4);
      const fx4 v = __builtin_nontemporal_load(src);
      c[0][j] = v.x; c[1][j] = v.y; c[2][j] = v.z; c[3][j] = v.w;
    }
    #pragma unroll
    for (int rr = 0; rr < 4; ++rr) {
      const int f = i4 + rr;
      uint4 pkv;
      pkv.x = pack_f16x2(c[rr][0], c[rr][1]);
      pkv.y = pack_f16x2(c[rr][2], c[rr][3]);
      pkv.z = pack_f16x2(c[rr][4], c[rr][5]);
      pkv.w = pack_f16x2(c[rr][6], c[rr][7]);
      *(uint4*)(&ldsx[f * BT]) = pkv;                           // full copy
      if (f < ALT)                                              // rotated copy
        *(uint4*)(&ldsx[(4096 + (f ^ ((f >> 3) & 7))) * BT]) = pkv;
    }
  }
  __syncthreads();

  const int wave = tid >> 6;
  const int lane = tid & 63;

  for (int g = wave; g < (OUT / 64); g += 16) {   // 4 groups per wave
    const int o = g * 64 + lane;
    const int4* wq = wt4 + o;                     // element k2 at wq[k2*OUT]

    __half2 acc0[4], acc1[4], acc2[4], acc3[4];   // 4 chains x 4 batch-pairs
    #pragma unroll
    for (int j = 0; j < 4; ++j) {
      acc0[j] = __float2half2_rn(0.f);
      acc1[j] = __float2half2_rn(0.f);
      acc2[j] = __float2half2_rn(0.f);
      acc3[j] = __float2half2_rn(0.f);
    }

    int4 p0 = wq[0];
    int4 p1 = wq[OUT];

    #pragma unroll
    for (int k2 = 0; k2 < (TK / 2); k2 += 2) {    // 4 k-entries per iter
      int4 n0, n1;
      if (k2 + 2 < (TK / 2)) {                    // prefetch next group (static)
        n0 = wq[(size_t)(k2 + 2) * OUT];
        n1 = wq[(size_t)(k2 + 3) * OUT];
      }
      const uint4 xa = *(const uint4*)(&ldsx[p0.x * BT]);   // quad-matched gathers
      const uint4 xb = *(const uint4*)(&ldsx[p0.z * BT]);
      const uint4 xc = *(const uint4*)(&ldsx[p1.x * BT]);
      const uint4 xd = *(const uint4*)(&ldsx[p1.z * BT]);
      const __half2 va = *(const __half2*)&p0.y;
      const __half2 vb = *(const __half2*)&p0.w;
      const __half2 vc = *(const __half2*)&p1.y;
      const __half2 vd = *(const __half2*)&p1.w;
      const __half2* ha = (const __half2*)&xa;
      const __half2* hb = (const __half2*)&xb;
      const __half2* hc = (const __half2*)&xc;
      const __half2* hd = (const __half2*)&xd;
      #pragma unroll
      for (int j = 0; j < 4; ++j) {
        acc0[j] = __hfma2(ha[j], va, acc0[j]);
        acc1[j] = __hfma2(hb[j], vb, acc1[j]);
        acc2[j] = __hfma2(hc[j], vc, acc2[j]);
        acc3[j] = __hfma2(hd[j], vd, acc3[j]);
      }
      if (k2 + 2 < (TK / 2)) { p0 = n0; p1 = n1; }
    }

    // epilogue: combine 4 fp16 chains in fp32, plain stores
    float* op = out + (size_t)b0 * OUT + o;
    #pragma unroll
    for (int j = 0; j < 4; ++j) {
      const float lo = (__low2float(acc0[j])  + __low2float(acc1[j])) +
                       (__low2float(acc2[j])  + __low2float(acc3[j]));
      const float hi = (__high2float(acc0[j]) + __high2float(acc1[j])) +
                       (__high2float(acc2[j]) + __high2float(acc3[j]));
      op[(size_t)(2 * j) * OUT]     = lo;
      op[(size_t)(2 * j + 1) * OUT] = hi;
    }
  }
}

// ---------------------------------------------------------------------------
extern "C" void kernel_launch(void* const* d_in, const int* in_sizes, int n_in,
                              void* d_out, int out_size, void* d_ws, size_t ws_size,
                              hipStream_t stream) {
  const float* x      = (const float*)d_in[0];
  const float* pre_w  = (const float*)d_in[1];
  const float* sign_m = (const float*)d_in[2];
  float* out = (float*)d_out;

  topk_build_kernel<<<OUT / 4, 256, 0, stream>>>(pre_w, sign_m, (int2*)d_ws);
  spmm_topk_kernel<<<BATCH / BT, 1024, 0, stream>>>(x, (const int4*)d_ws, out);
}